// Round 2
// baseline (208.869 us; speedup 1.0000x reference)
//
#include <hip/hip_runtime.h>
#include <hip/hip_bf16.h>

// bs=2, seq=2048, d_model=512, heads=8, d_k=64, WINDOW=2
#define SEQ 2048
#define DM  512
#define BS  2
#define NH  8
#define DK  64
#define MROWS (BS * SEQ)   // 4096
#define GK 64              // GEMM K-tile (two 16x16x32 MFMA k-steps per barrier pair)

typedef __attribute__((ext_vector_type(8))) short bf16x8;
typedef __attribute__((ext_vector_type(4))) float f32x4;

__device__ __forceinline__ unsigned short f2bf(float f) {
    unsigned int u = __float_as_uint(f);
    u += 0x7fff + ((u >> 16) & 1);
    return (unsigned short)(u >> 16);
}
__device__ __forceinline__ float bf2f(unsigned short b) {
    return __uint_as_float((unsigned int)b << 16);
}

// async global->LDS, 16B per lane. LDS dest must be wave-uniform base + lane*16.
#define GLDS16(g, l) __builtin_amdgcn_global_load_lds( \
    (const __attribute__((address_space(1))) void*)(g), \
    (__attribute__((address_space(3))) void*)(unsigned int)(unsigned long long)(l), 16, 0, 0)

// Device-scope grid barrier for persistent (all-resident) grids.
// Release fetch_add -> relaxed spin -> acquire load: compiler emits the
// agent-scope cache ops (buffer_wbl2 / buffer_inv sc1) for cross-XCD visibility.
__device__ __forceinline__ void gridbar(unsigned int* ctr, unsigned int target) {
    __syncthreads();
    if (threadIdx.x == 0) {
        __hip_atomic_fetch_add(ctr, 1u, __ATOMIC_RELEASE, __HIP_MEMORY_SCOPE_AGENT);
        while (__hip_atomic_load(ctr, __ATOMIC_RELAXED, __HIP_MEMORY_SCOPE_AGENT) < target)
            __builtin_amdgcn_s_sleep(2);
        (void)__hip_atomic_load(ctr, __ATOMIC_ACQUIRE, __HIP_MEMORY_SCOPE_AGENT);
    }
    __syncthreads();
}

// ================= Kernel A: weight prep + QKV projection (one grid, one barrier) ==========
// Phase 0: 1024 32x32 transpose+cvt tiles strided over 768 blocks; vsum = SEQ*bv init.
// Phase 1: R0's gemm_qkv_cvt verbatim (64x128 tile, GK=64, XCD-swizzled 768 grid,
//          3 blocks/CU), with A-staging cvt via v_cvt_pk_bf16_f32 (bit-identical RNE,
//          8 instr instead of ~56 per wave per K-iter).
__global__ __launch_bounds__(256, 3) void prep_qkv(
    const float* __restrict__ q, const float* __restrict__ k, const float* __restrict__ v,
    const float* __restrict__ Wq, const float* __restrict__ Wk,
    const float* __restrict__ Wv, const float* __restrict__ Wo,
    const float* __restrict__ bq, const float* __restrict__ bk, const float* __restrict__ bv_,
    unsigned short* __restrict__ WqT, unsigned short* __restrict__ WkT,
    unsigned short* __restrict__ WvT, unsigned short* __restrict__ WoT,
    unsigned short* __restrict__ Qb, unsigned short* __restrict__ Kb,
    unsigned short* __restrict__ Vb,
    float* __restrict__ vsum, unsigned int* __restrict__ ctr)
{
    __shared__ __align__(16) unsigned char SMEM[24576];

    // ---------------- phase 0: transpose+cvt weights, init vsum ----------------
    {
        float (*tile)[33] = (float (*)[33])SMEM;
        if (blockIdx.x == 0) {
            #pragma unroll
            for (int t = 0; t < 4; ++t) {
                const int idx = threadIdx.x * 4 + t;           // 0..1023
                vsum[idx] = (float)SEQ * bv_[idx & (DM - 1)];
            }
        }
        const int tx = threadIdx.x & 31;
        const int ty = threadIdx.x >> 5;
        for (int tt = blockIdx.x; tt < 1024; tt += 768) {
            const int z = tt >> 8;
            const int tl = tt & 255;
            const float* W = (z == 0) ? Wq : (z == 1) ? Wk : (z == 2) ? Wv : Wo;
            unsigned short* T = (z == 0) ? WqT : (z == 1) ? WkT : (z == 2) ? WvT : WoT;
            const int n0 = (tl & 15) * 32, k0 = (tl >> 4) * 32;
            #pragma unroll
            for (int r = 0; r < 32; r += 8)
                tile[ty + r][tx] = W[(size_t)(k0 + ty + r) * DM + n0 + tx];
            __syncthreads();
            #pragma unroll
            for (int r = 0; r < 32; r += 8)
                T[(size_t)(n0 + ty + r) * DM + k0 + tx] = f2bf(tile[tx][ty + r]);
            __syncthreads();
        }
    }

    gridbar(ctr, 768);   // WqT/WkT/WvT + vsum visible device-wide

    // ---------------- phase 1: QKV projection GEMM ----------------
    unsigned short* S = (unsigned short*)SMEM;   // A: [kk][row64][32] 8KB; B at 4096: 16KB

    const int g = blockIdx.x;                 // 0..767
    const int xcd   = g & 7;
    const int n_idx = (g >> 3) & 3;
    const int t     = g >> 5;                 // 0..23
    const int strip = t * 8 + xcd;            // 0..191
    const int z     = strip >> 6;             // 0..2
    const int m0    = (strip & 63) * 64;
    const int n0    = n_idx * 128;

    const float* Af; const unsigned short* BT; const float* bias; unsigned short* C; float* vs;
    if (z == 0)      { Af = q; BT = WqT; bias = bq; C = Qb; vs = nullptr; }
    else if (z == 1) { Af = k; BT = WkT; bias = bk; C = Kb; vs = nullptr; }
    else             { Af = v; BT = WvT; bias = bv_; C = Vb; vs = vsum; }

    const int tid  = threadIdx.x;
    const int lane = tid & 63;
    const int wave = tid >> 6;
    const int wm = (wave & 1) * 32;       // wave tile 32x64
    const int wn = (wave >> 1) * 64;
    const int l15 = lane & 15;
    const int q8  = (lane >> 4) * 8;

    f32x4 acc[2][4];
    #pragma unroll
    for (int i = 0; i < 2; ++i)
        #pragma unroll
        for (int j = 0; j < 4; ++j)
            acc[i][j] = (f32x4){0.f, 0.f, 0.f, 0.f};

    // A-staging mapping: pass p in [0,4): row = p*16 + (tid>>4), cols (tid&15)*4 .. +3
    const int arow = tid >> 4;             // 0..15
    const int akl  = (tid & 15) * 4;       // 0..60
    const int awoff = ((akl >> 5) * 2048) + (akl & 31);   // + row*32 (shorts); kk stride 2048

    // B chunks: 1024 x 16B per K-tile, 4 per thread.  LDS B region [kk][n][32].
    const unsigned short* gb[4];
    unsigned short* lb[4];
    #pragma unroll
    for (int it = 0; it < 4; ++it) {
        const int c = tid + it * 256;
        const int n  = (c >> 2) & 127;
        const int kk = c >> 9;
        gb[it] = BT + (size_t)(n0 + n) * DM + kk * 32 + (c & 3) * 8;
        lb[it] = &S[4096 + c * 8];
    }

    for (int k0 = 0; k0 < DM; k0 += GK) {
        #pragma unroll
        for (int it = 0; it < 4; ++it)
            GLDS16(gb[it] + k0, lb[it]);

        float4 av[4];
        #pragma unroll
        for (int p = 0; p < 4; ++p)
            av[p] = *(const float4*)(Af + (size_t)(m0 + p * 16 + arow) * DM + k0 + akl);
        #pragma unroll
        for (int p = 0; p < 4; ++p) {
            unsigned int u0, u1;
            asm("v_cvt_pk_bf16_f32 %0, %1, %2" : "=v"(u0) : "v"(av[p].x), "v"(av[p].y));
            asm("v_cvt_pk_bf16_f32 %0, %1, %2" : "=v"(u1) : "v"(av[p].z), "v"(av[p].w));
            uint2 o; o.x = u0; o.y = u1;
            *(uint2*)&S[awoff + (p * 16 + arow) * 32] = o;
        }
        __syncthreads();

        #pragma unroll
        for (int kk = 0; kk < 2; ++kk) {
            bf16x8 af[2], bfr[4];
            #pragma unroll
            for (int i = 0; i < 2; ++i)
                af[i] = *(const bf16x8*)&S[kk * 2048 + (wm + i * 16 + l15) * 32 + q8];
            #pragma unroll
            for (int j = 0; j < 4; ++j)
                bfr[j] = *(const bf16x8*)&S[4096 + kk * 4096 + (wn + j * 16 + l15) * 32 + q8];
            #pragma unroll
            for (int i = 0; i < 2; ++i)
                #pragma unroll
                for (int j = 0; j < 4; ++j)
                    acc[i][j] = __builtin_amdgcn_mfma_f32_16x16x32_bf16(af[i], bfr[j], acc[i][j], 0, 0, 0);
        }
        __syncthreads();
    }

    // epilogue: C/D layout col=lane&15, row=(lane>>4)*4+reg; bf16 store
    #pragma unroll
    for (int j = 0; j < 4; ++j) {
        const int col = n0 + wn + j * 16 + l15;
        const float bvv = bias[col];
        #pragma unroll
        for (int i = 0; i < 2; ++i) {
            const int rbase = m0 + wm + i * 16 + (lane >> 4) * 4;
            #pragma unroll
            for (int r = 0; r < 4; ++r)
                C[(size_t)(rbase + r) * DM + col] = f2bf(acc[i][j][r] + bvv);
        }
    }

    if (vs) {
        const int b = m0 >> 11;   // 64-row tiles never straddle the batch boundary
        #pragma unroll
        for (int j = 0; j < 4; ++j) {
            float part = 0.f;
            #pragma unroll
            for (int i = 0; i < 2; ++i)
                #pragma unroll
                for (int r = 0; r < 4; ++r)
                    part += acc[i][j][r];
            part += __shfl_xor(part, 16, 64);
            part += __shfl_xor(part, 32, 64);
            if ((lane >> 4) == 0)
                atomicAdd(&vs[b * DM + n0 + wn + j * 16 + l15], part);
        }
    }
}

// ================= Kernel B: band attention + output projection (one grid, one barrier) =====
// Phase 0: 2048 attention units = 512 blocks x 4 waves EXACTLY (same 8 waves/CU as the
//          proven split version; waves fully independent, adjacent q-tiles per block
//          share K/V rows for L1 locality). Writes bf16 concat to global.
// Phase 1: R0's gemm_out verbatim (64x64 tiles, XCD-swizzled 512 grid, 2 blocks/CU).
__global__ __launch_bounds__(256, 2) void attn_out2(
    const unsigned short* __restrict__ Qb, const unsigned short* __restrict__ Kb,
    const unsigned short* __restrict__ Vb, const float* __restrict__ vsum,
    const unsigned short* __restrict__ WoT, const float* __restrict__ bo,
    unsigned short* __restrict__ concat, float* __restrict__ out,
    unsigned int* __restrict__ ctr)
{
    __shared__ __align__(16) unsigned char SMEM[16384];

    // ---------------- phase 0: band attention, one wave per (b,h,q-tile) ----------------
    {
        unsigned short* Wlds = (unsigned short*)SMEM + (threadIdx.x >> 6) * 512; // per-wave 1KB
        const int lane = threadIdx.x & 63;
        const int l15  = lane & 15;
        const int quad = lane >> 4;                // 0..3
        const int u  = blockIdx.x * 4 + (threadIdx.x >> 6);   // 0..2047
        const int bh = u >> 7;
        const int b = bh >> 3, h = bh & 7;
        const int q0 = (u & 127) * 16;
        const size_t rowbase = (size_t)b * SEQ;
        const int dbase = h * DK;

        const unsigned short* qrow = Qb + (rowbase + q0 + l15) * DM + dbase + quad * 8;
        const bf16x8 aq0 = *(const bf16x8*)(qrow);
        const bf16x8 aq1 = *(const bf16x8*)(qrow + 32);

        f32x4 sc[2];
        #pragma unroll
        for (int t = 0; t < 2; ++t) {
            int kp = q0 - 4 + t * 16 + l15;
            kp = min(max(kp, 0), SEQ - 1);
            const unsigned short* krow = Kb + (rowbase + kp) * DM + dbase + quad * 8;
            const bf16x8 b0 = *(const bf16x8*)(krow);
            const bf16x8 b1 = *(const bf16x8*)(krow + 32);
            f32x4 z = (f32x4){0.f, 0.f, 0.f, 0.f};
            z = __builtin_amdgcn_mfma_f32_16x16x32_bf16(aq0, b0, z, 0, 0, 0);
            sc[t] = __builtin_amdgcn_mfma_f32_16x16x32_bf16(aq1, b1, z, 0, 0, 0);
        }

        float dsum[4] = {0.f, 0.f, 0.f, 0.f};
        #pragma unroll
        for (int t = 0; t < 2; ++t) {
            const int kpos = q0 - 4 + t * 16 + l15;   // unclamped
            #pragma unroll
            for (int r = 0; r < 4; ++r) {
                const int qq = q0 + quad * 4 + r;
                const int mn = min(qq, kpos), mx = qq + kpos - mn;
                const float cnt = (float)(min(mn + 2, SEQ - 1) - max(mx - 2, 0) + 1);
                const float cw = (kpos >= 0 && kpos < SEQ && (mx - mn) <= 4) ? cnt * 0.125f : 0.f;
                const float w = expf(sc[t][r] * cw) - 1.f;   // cw==0 -> exactly 0
                const unsigned short wb = f2bf(w);
                Wlds[(quad * 4 + r) * 32 + t * 16 + l15] = wb;
                dsum[r] += bf2f(wb);
            }
        }
        #pragma unroll
        for (int off = 1; off <= 8; off <<= 1)
            #pragma unroll
            for (int r = 0; r < 4; ++r)
                dsum[r] += __shfl_xor(dsum[r], off, 64);

        __syncthreads();   // per-wave Wlds regions; barrier doubles as LDS fence
        const bf16x8 aw = *(const bf16x8*)&Wlds[l15 * 32 + quad * 8];

        #pragma unroll
        for (int nt = 0; nt < 4; ++nt) {
            const int d = dbase + nt * 16 + l15;
            bf16x8 bv_;
            #pragma unroll
            for (int j = 0; j < 8; ++j) {
                int kr = q0 - 4 + quad * 8 + j;
                kr = min(max(kr, 0), SEQ - 1);       // pad rows get w=0
                bv_[j] = (short)Vb[(rowbase + kr) * DM + d];
            }
            f32x4 z = (f32x4){0.f, 0.f, 0.f, 0.f};
            const f32x4 o = __builtin_amdgcn_mfma_f32_16x16x32_bf16(aw, bv_, z, 0, 0, 0);
            const float vsv = vsum[b * DM + d];
            #pragma unroll
            for (int r = 0; r < 4; ++r) {
                const float den = (float)SEQ + dsum[r];
                concat[(rowbase + q0 + quad * 4 + r) * DM + d] = f2bf((vsv + o[r]) / den);
            }
        }
    }

    gridbar(ctr, 512);   // concat visible device-wide

    // ---------------- phase 1: output projection, 64x64 tile ----------------
    {
        unsigned short* S = (unsigned short*)SMEM;   // (64+64)*64 shorts = 16 KB
        const int g = blockIdx.x;                // 0..511
        const int xcd   = g & 7;
        const int n_idx = (g >> 3) & 7;
        const int m_idx = (g >> 6) * 8 + xcd;    // 0..63
        const int m0 = m_idx * 64, n0 = n_idx * 64;

        const int tid  = threadIdx.x;
        const int lane = tid & 63;
        const int wave = tid >> 6;
        const int wm = (wave & 1) * 32;          // WAVES_M=2
        const int wn = (wave >> 1) * 32;
        const int l15 = lane & 15;
        const int q8  = (lane >> 4) * 8;

        f32x4 acc[2][2];
        #pragma unroll
        for (int i = 0; i < 2; ++i)
            #pragma unroll
            for (int j = 0; j < 2; ++j)
                acc[i][j] = (f32x4){0.f, 0.f, 0.f, 0.f};

        // 1024 x 16B chunks per K-tile, 4 per thread.  A region [kk][row64][32]; B at 4096.
        const unsigned short* gp[4];
        unsigned short* lp[4];
        #pragma unroll
        for (int it = 0; it < 4; ++it) {
            const int c = tid + it * 256;
            if (c < 512) {
                const int kk = c >> 8;
                const int cr = c & 255;
                gp[it] = concat + (size_t)(m0 + (cr >> 2)) * DM + kk * 32 + (c & 3) * 8;
            } else {
                const int cb = c - 512;
                const int kk = cb >> 8;
                const int cr = cb & 255;
                gp[it] = WoT + (size_t)(n0 + (cr >> 2)) * DM + kk * 32 + (cb & 3) * 8;
            }
            lp[it] = &S[(size_t)c * 8];
        }

        for (int k0 = 0; k0 < DM; k0 += GK) {
            #pragma unroll
            for (int it = 0; it < 4; ++it)
                GLDS16(gp[it] + k0, lp[it]);
            __syncthreads();

            #pragma unroll
            for (int kk = 0; kk < 2; ++kk) {
                bf16x8 af[2], bfr[2];
                #pragma unroll
                for (int i = 0; i < 2; ++i)
                    af[i] = *(const bf16x8*)&S[kk * 2048 + (wm + i * 16 + l15) * 32 + q8];
                #pragma unroll
                for (int j = 0; j < 2; ++j)
                    bfr[j] = *(const bf16x8*)&S[4096 + kk * 2048 + (wn + j * 16 + l15) * 32 + q8];
                #pragma unroll
                for (int i = 0; i < 2; ++i)
                    #pragma unroll
                    for (int j = 0; j < 2; ++j)
                        acc[i][j] = __builtin_amdgcn_mfma_f32_16x16x32_bf16(af[i], bfr[j], acc[i][j], 0, 0, 0);
            }
            __syncthreads();
        }

        #pragma unroll
        for (int j = 0; j < 2; ++j) {
            const int col = n0 + wn + j * 16 + l15;
            const float bov = bo[col];
            #pragma unroll
            for (int i = 0; i < 2; ++i) {
                const int rbase = m0 + wm + i * 16 + (lane >> 4) * 4;
                #pragma unroll
                for (int r = 0; r < 4; ++r)
                    out[(size_t)(rbase + r) * DM + col] = acc[i][j][r] + bov;
            }
        }
    }
}

extern "C" void kernel_launch(void* const* d_in, const int* in_sizes, int n_in,
                              void* d_out, int out_size, void* d_ws, size_t ws_size,
                              hipStream_t stream) {
    const float* q  = (const float*)d_in[0];
    const float* k  = (const float*)d_in[1];
    const float* v  = (const float*)d_in[2];
    const float* Wq = (const float*)d_in[3];
    const float* bq = (const float*)d_in[4];
    const float* Wk = (const float*)d_in[5];
    const float* bk = (const float*)d_in[6];
    const float* Wv = (const float*)d_in[7];
    const float* bv = (const float*)d_in[8];
    const float* Wo = (const float*)d_in[9];
    const float* bo = (const float*)d_in[10];

    const size_t NE = (size_t)MROWS * DM;  // 2,097,152

    unsigned int* ctrs = (unsigned int*)d_ws;          // 16 uints (64 B)
    float* vsum = (float*)d_ws + 16;                   // 1024 floats
    unsigned short* Qb     = (unsigned short*)(vsum + 1024);
    unsigned short* Kb     = Qb + NE;
    unsigned short* Vb     = Kb + NE;
    unsigned short* WqT    = Vb + NE;
    unsigned short* WkT    = WqT + DM * DM;
    unsigned short* WvT    = WkT + DM * DM;
    unsigned short* WoT    = WvT + DM * DM;
    unsigned short* concat = WoT + DM * DM;

    // zero the grid-barrier counters (workspace is re-poisoned every iteration)
    hipMemsetAsync(d_ws, 0, 64, stream);

    // A. weight prep + QKV projection (768 blocks, 3/CU, internal grid barrier)
    prep_qkv<<<768, 256, 0, stream>>>(q, k, v, Wq, Wk, Wv, Wo, bq, bk, bv,
                                      WqT, WkT, WvT, WoT, Qb, Kb, Vb, vsum, &ctrs[0]);

    // B. band attention + output projection (512 blocks, 2/CU, internal grid barrier)
    attn_out2<<<512, 256, 0, stream>>>(Qb, Kb, Vb, vsum, WoT, bo, concat,
                                       (float*)d_out, &ctrs[1]);
}

// Round 3
// 113.455 us; speedup vs baseline: 1.8410x; 1.8410x over previous
//
#include <hip/hip_runtime.h>
#include <hip/hip_bf16.h>

// bs=2, seq=2048, d_model=512, heads=8, d_k=64, WINDOW=2
#define SEQ 2048
#define DM  512
#define BS  2
#define NH  8
#define DK  64
#define MROWS (BS * SEQ)   // 4096
#define GK 64              // GEMM K-tile (two 16x16x32 MFMA k-steps per barrier)

typedef __attribute__((ext_vector_type(8))) short bf16x8;
typedef __attribute__((ext_vector_type(4))) float f32x4;

__device__ __forceinline__ unsigned short f2bf(float f) {
    unsigned int u = __float_as_uint(f);
    u += 0x7fff + ((u >> 16) & 1);
    return (unsigned short)(u >> 16);
}
__device__ __forceinline__ float bf2f(unsigned short b) {
    return __uint_as_float((unsigned int)b << 16);
}

// async global->LDS, 16B per lane. LDS dest must be wave-uniform base + lane*16.
#define GLDS16(g, l) __builtin_amdgcn_global_load_lds( \
    (const __attribute__((address_space(1))) void*)(g), \
    (__attribute__((address_space(3))) void*)(unsigned int)(unsigned long long)(l), 16, 0, 0)

// ---------------- prep (small): transpose+cvt weights; init vsum = SEQ*bv ----------------
__global__ __launch_bounds__(256) void prep_w(const float* __restrict__ Wq, const float* __restrict__ Wk,
                                              const float* __restrict__ Wv, const float* __restrict__ Wo,
                                              const float* __restrict__ bv_,
                                              unsigned short* __restrict__ WqT, unsigned short* __restrict__ WkT,
                                              unsigned short* __restrict__ WvT, unsigned short* __restrict__ WoT,
                                              float* __restrict__ vsum)
{
    __shared__ float tile[32][33];
    const int bid = blockIdx.x;            // 0..1023
    if (bid == 0) {
        #pragma unroll
        for (int t = 0; t < 4; ++t) {
            const int idx = threadIdx.x * 4 + t;           // 0..1023
            vsum[idx] = (float)SEQ * bv_[idx & (DM - 1)];
        }
    }
    const int z = bid >> 8;
    const int tl = bid & 255;
    const float* W = (z == 0) ? Wq : (z == 1) ? Wk : (z == 2) ? Wv : Wo;
    unsigned short* T = (z == 0) ? WqT : (z == 1) ? WkT : (z == 2) ? WvT : WoT;
    const int n0 = (tl & 15) * 32, k0 = (tl >> 4) * 32;
    const int tx = threadIdx.x & 31;
    const int ty = threadIdx.x >> 5;
    #pragma unroll
    for (int r = 0; r < 32; r += 8)
        tile[ty + r][tx] = W[(size_t)(k0 + ty + r) * DM + n0 + tx];
    __syncthreads();
    #pragma unroll
    for (int r = 0; r < 32; r += 8)
        T[(size_t)(n0 + ty + r) * DM + k0 + tx] = f2bf(tile[tx][ty + r]);
}

// ---------------- QKV projection GEMM: 2-phase double-buffered pipeline ----------------
// C(bf16, 4096x512) = cvt_bf16(A f32) @ BT(bf16)^T + bias.  Tile 64x128, GK=64.
// 1D grid 768, XCD-swizzled. Double-buffered LDS (2x24KB, 3 blocks/CU):
// per iter: issue next-tile GLDS16 (B) + f32 A loads FIRST, compute current tile
// (16 MFMA), then cvt_pk+ds_write next A, ONE barrier. Latency hides under MFMA.
__global__ __launch_bounds__(256) void gemm_qkv_cvt(const float* __restrict__ q,
                                                    const float* __restrict__ k,
                                                    const float* __restrict__ v,
                                                    const unsigned short* __restrict__ WqT,
                                                    const unsigned short* __restrict__ WkT,
                                                    const unsigned short* __restrict__ WvT,
                                                    const float* __restrict__ bq, const float* __restrict__ bk,
                                                    const float* __restrict__ bvp,
                                                    unsigned short* __restrict__ Qb, unsigned short* __restrict__ Kb,
                                                    unsigned short* __restrict__ Vb, float* __restrict__ vsum)
{
    // per buffer: A region [kk][row64][32] = 4096 shorts (8 KB); B at 4096: [kk][row128][32] (16 KB)
    __shared__ unsigned short S[2][12288];

    // XCD swizzle decode: g = xcd + 8*n + 32*t; strip = t*8+xcd; z = strip/64, m = strip%64
    const int g = blockIdx.x;                 // 0..767
    const int xcd   = g & 7;
    const int n_idx = (g >> 3) & 3;
    const int t_    = g >> 5;                 // 0..23
    const int strip = t_ * 8 + xcd;           // 0..191
    const int z     = strip >> 6;             // 0..2
    const int m0    = (strip & 63) * 64;
    const int n0    = n_idx * 128;

    const float* Af; const unsigned short* BT; const float* bias; unsigned short* C; float* vs;
    if (z == 0)      { Af = q; BT = WqT; bias = bq; C = Qb; vs = nullptr; }
    else if (z == 1) { Af = k; BT = WkT; bias = bk; C = Kb; vs = nullptr; }
    else             { Af = v; BT = WvT; bias = bvp; C = Vb; vs = vsum; }

    const int tid  = threadIdx.x;
    const int lane = tid & 63;
    const int wave = tid >> 6;
    const int wm = (wave & 1) * 32;       // wave tile 32x64
    const int wn = (wave >> 1) * 64;
    const int l15 = lane & 15;
    const int q8  = (lane >> 4) * 8;

    f32x4 acc[2][4];
    #pragma unroll
    for (int i = 0; i < 2; ++i)
        #pragma unroll
        for (int j = 0; j < 4; ++j)
            acc[i][j] = (f32x4){0.f, 0.f, 0.f, 0.f};

    // A-staging mapping: pass p in [0,4): row = p*16 + (tid>>4), cols (tid&15)*4 .. +3
    const int arow = tid >> 4;             // 0..15
    const int akl  = (tid & 15) * 4;       // 0..60
    const int awoff = ((akl >> 5) * 2048) + (akl & 31);   // + row*32 (shorts); kk stride 2048
    const float* agp = Af + (size_t)(m0 + arow) * DM + akl;   // + p*16*DM + k0

    // B chunks: 1024 x 16B per K-tile, 4 per thread.  LDS B region [kk][n][32].
    const unsigned short* gb[4];
    int lboff[4];
    #pragma unroll
    for (int it = 0; it < 4; ++it) {
        const int c = tid + it * 256;
        const int n  = (c >> 2) & 127;
        const int kk = c >> 9;
        gb[it] = BT + (size_t)(n0 + n) * DM + kk * 32 + (c & 3) * 8;
        lboff[it] = 4096 + c * 8;
    }

    // ---- prologue: stage tile 0 into buf 0 ----
    {
        #pragma unroll
        for (int it = 0; it < 4; ++it)
            GLDS16(gb[it], &S[0][lboff[it]]);
        float4 av[4];
        #pragma unroll
        for (int p = 0; p < 4; ++p)
            av[p] = *(const float4*)(agp + (size_t)p * 16 * DM);
        #pragma unroll
        for (int p = 0; p < 4; ++p) {
            unsigned int u0, u1;
            asm("v_cvt_pk_bf16_f32 %0, %1, %2" : "=v"(u0) : "v"(av[p].x), "v"(av[p].y));
            asm("v_cvt_pk_bf16_f32 %0, %1, %2" : "=v"(u1) : "v"(av[p].z), "v"(av[p].w));
            uint2 o; o.x = u0; o.y = u1;
            *(uint2*)&S[0][awoff + (p * 16 + arow) * 32] = o;
        }
    }
    __syncthreads();

    for (int t = 0; t < 8; ++t) {
        const int cur = t & 1, nxt = cur ^ 1;
        const int k0n = (t + 1) * GK;
        float4 av[4];
        if (t < 7) {
            #pragma unroll
            for (int it = 0; it < 4; ++it)
                GLDS16(gb[it] + k0n, &S[nxt][lboff[it]]);
            #pragma unroll
            for (int p = 0; p < 4; ++p)
                av[p] = *(const float4*)(agp + (size_t)p * 16 * DM + k0n);
        }

        #pragma unroll
        for (int kk = 0; kk < 2; ++kk) {
            bf16x8 af[2], bfr[4];
            #pragma unroll
            for (int i = 0; i < 2; ++i)
                af[i] = *(const bf16x8*)&S[cur][kk * 2048 + (wm + i * 16 + l15) * 32 + q8];
            #pragma unroll
            for (int j = 0; j < 4; ++j)
                bfr[j] = *(const bf16x8*)&S[cur][4096 + kk * 4096 + (wn + j * 16 + l15) * 32 + q8];
            #pragma unroll
            for (int i = 0; i < 2; ++i)
                #pragma unroll
                for (int j = 0; j < 4; ++j)
                    acc[i][j] = __builtin_amdgcn_mfma_f32_16x16x32_bf16(af[i], bfr[j], acc[i][j], 0, 0, 0);
        }

        if (t < 7) {
            #pragma unroll
            for (int p = 0; p < 4; ++p) {
                unsigned int u0, u1;
                asm("v_cvt_pk_bf16_f32 %0, %1, %2" : "=v"(u0) : "v"(av[p].x), "v"(av[p].y));
                asm("v_cvt_pk_bf16_f32 %0, %1, %2" : "=v"(u1) : "v"(av[p].z), "v"(av[p].w));
                uint2 o; o.x = u0; o.y = u1;
                *(uint2*)&S[nxt][awoff + (p * 16 + arow) * 32] = o;
            }
        }
        __syncthreads();   // drains GLDS16 (vmcnt) + ds_writes (lgkm); buf[nxt] ready
    }

    // epilogue: C/D layout col=lane&15, row=(lane>>4)*4+reg; bf16 store
    #pragma unroll
    for (int j = 0; j < 4; ++j) {
        const int col = n0 + wn + j * 16 + l15;
        const float bv = bias[col];
        #pragma unroll
        for (int i = 0; i < 2; ++i) {
            const int rbase = m0 + wm + i * 16 + (lane >> 4) * 4;
            #pragma unroll
            for (int r = 0; r < 4; ++r)
                C[(size_t)(rbase + r) * DM + col] = f2bf(acc[i][j][r] + bv);
        }
    }

    if (vs) {
        const int b = m0 >> 11;   // 64-row tiles never straddle the batch boundary
        #pragma unroll
        for (int j = 0; j < 4; ++j) {
            float part = 0.f;
            #pragma unroll
            for (int i = 0; i < 2; ++i)
                #pragma unroll
                for (int r = 0; r < 4; ++r)
                    part += acc[i][j][r];
            part += __shfl_xor(part, 16, 64);
            part += __shfl_xor(part, 32, 64);
            if ((lane >> 4) == 0)
                atomicAdd(&vs[b * DM + n0 + wn + j * 16 + l15], part);
        }
    }
}

// ---------------- MFMA band attention ----------------
// One wave per (b,h, 16-q tile). V rows [q0-4, q0+27] x 64 cols prefetched as 4
// coalesced b128 loads BEFORE the QK phase (latency hides under QK math), parked
// in regs, ds_write_b128 into pad-70 LDS tile (quad-rows land on disjoint 8-bank
// groups -> gather ds_read_u16 is 2-way = conflict-free), replacing the old
// 32 scalar global u16 gathers.  out_row = (vsum + sum w*v) / (SEQ + sum w)
__global__ __launch_bounds__(64) void attn_mfma(const unsigned short* __restrict__ Qb,
                                                const unsigned short* __restrict__ Kb,
                                                const unsigned short* __restrict__ Vb,
                                                const float* __restrict__ vsum,
                                                unsigned short* __restrict__ concat)
{
    __shared__ unsigned short Wlds[16 * 32];   // [q_local][kpos_local]
    __shared__ unsigned short Vt[32 * 70];     // V tile, pad 70 (140B rows)
    const int lane = threadIdx.x;              // 0..63
    const int l15  = lane & 15;
    const int quad = lane >> 4;                // 0..3
    const int bh = blockIdx.y;
    const int b = bh >> 3, h = bh & 7;
    const int q0 = blockIdx.x * 16;
    const size_t rowbase = (size_t)b * SEQ;
    const int dbase = h * DK;

    // -------- V prefetch: rows q0-4 .. q0+27, 64 cols; 4 x b128 per lane --------
    bf16x8 vv[4];
    #pragma unroll
    for (int p = 0; p < 4; ++p) {
        const int idx = p * 64 + lane;
        const int row = idx >> 3, c8 = idx & 7;
        int kr = q0 - 4 + row;
        kr = min(max(kr, 0), SEQ - 1);           // pad rows get w=0
        vv[p] = *(const bf16x8*)&Vb[(rowbase + kr) * DM + dbase + c8 * 8];
    }

    // -------- QK^T + band weights --------
    const unsigned short* qrow = Qb + (rowbase + q0 + l15) * DM + dbase + quad * 8;
    const bf16x8 aq0 = *(const bf16x8*)(qrow);
    const bf16x8 aq1 = *(const bf16x8*)(qrow + 32);

    f32x4 sc[2];
    #pragma unroll
    for (int t = 0; t < 2; ++t) {
        int kp = q0 - 4 + t * 16 + l15;
        kp = min(max(kp, 0), SEQ - 1);
        const unsigned short* krow = Kb + (rowbase + kp) * DM + dbase + quad * 8;
        const bf16x8 b0 = *(const bf16x8*)(krow);
        const bf16x8 b1 = *(const bf16x8*)(krow + 32);
        f32x4 z = (f32x4){0.f, 0.f, 0.f, 0.f};
        z = __builtin_amdgcn_mfma_f32_16x16x32_bf16(aq0, b0, z, 0, 0, 0);
        sc[t] = __builtin_amdgcn_mfma_f32_16x16x32_bf16(aq1, b1, z, 0, 0, 0);
    }

    float dsum[4] = {0.f, 0.f, 0.f, 0.f};
    #pragma unroll
    for (int t = 0; t < 2; ++t) {
        const int kpos = q0 - 4 + t * 16 + l15;   // unclamped
        #pragma unroll
        for (int r = 0; r < 4; ++r) {
            const int qq = q0 + quad * 4 + r;
            const int mn = min(qq, kpos), mx = qq + kpos - mn;
            const float cnt = (float)(min(mn + 2, SEQ - 1) - max(mx - 2, 0) + 1);
            const float cw = (kpos >= 0 && kpos < SEQ && (mx - mn) <= 4) ? cnt * 0.125f : 0.f;
            const float w = expf(sc[t][r] * cw) - 1.f;   // cw==0 -> exactly 0
            const unsigned short wb = f2bf(w);
            Wlds[(quad * 4 + r) * 32 + t * 16 + l15] = wb;
            dsum[r] += bf2f(wb);
        }
    }
    #pragma unroll
    for (int off = 1; off <= 8; off <<= 1)
        #pragma unroll
        for (int r = 0; r < 4; ++r)
            dsum[r] += __shfl_xor(dsum[r], off, 64);

    // -------- park prefetched V into padded LDS --------
    #pragma unroll
    for (int p = 0; p < 4; ++p) {
        const int idx = p * 64 + lane;
        const int row = idx >> 3, c8 = idx & 7;
        *(bf16x8*)&Vt[row * 70 + c8 * 8] = vv[p];
    }
    __syncthreads();

    const bf16x8 aw = *(const bf16x8*)&Wlds[l15 * 32 + quad * 8];

    #pragma unroll
    for (int nt = 0; nt < 4; ++nt) {
        const int dl = nt * 16 + l15;
        bf16x8 bv_;
        #pragma unroll
        for (int j = 0; j < 8; ++j)
            bv_[j] = (short)Vt[(quad * 8 + j) * 70 + dl];
        f32x4 z = (f32x4){0.f, 0.f, 0.f, 0.f};
        const f32x4 o = __builtin_amdgcn_mfma_f32_16x16x32_bf16(aw, bv_, z, 0, 0, 0);
        const float vs = vsum[b * DM + dbase + dl];
        #pragma unroll
        for (int r = 0; r < 4; ++r) {
            const float den = (float)SEQ + dsum[r];
            concat[(rowbase + q0 + quad * 4 + r) * DM + dbase + dl] = f2bf((vs + o[r]) / den);
        }
    }
}

// ---------------- output projection: 64x64 tile, 2-phase double-buffered ----------------
// 1D grid 512, XCD-swizzled.  LDS 2x16KB (2 blocks/CU); next K-tile's GLDS16
// issued before the current tile's MFMA, one barrier per iter.
__global__ __launch_bounds__(256) void gemm_out(const unsigned short* __restrict__ A,
                                                const unsigned short* __restrict__ BT,
                                                const float* __restrict__ bias,
                                                float* __restrict__ C)
{
    __shared__ unsigned short S[2][8192];   // per buf: A [kk][row64][32] 4096; B at 4096

    const int g = blockIdx.x;                // 0..511
    const int xcd   = g & 7;
    const int n_idx = (g >> 3) & 7;
    const int m_idx = (g >> 6) * 8 + xcd;    // 0..63
    const int m0 = m_idx * 64, n0 = n_idx * 64;

    const int tid  = threadIdx.x;
    const int lane = tid & 63;
    const int wave = tid >> 6;
    const int wm = (wave & 1) * 32;          // WAVES_M=2
    const int wn = (wave >> 1) * 32;
    const int l15 = lane & 15;
    const int q8  = (lane >> 4) * 8;

    f32x4 acc[2][2];
    #pragma unroll
    for (int i = 0; i < 2; ++i)
        #pragma unroll
        for (int j = 0; j < 2; ++j)
            acc[i][j] = (f32x4){0.f, 0.f, 0.f, 0.f};

    // 1024 x 16B chunks per K-tile, 4 per thread: A 512 (c<512), B 512.
    const unsigned short* gp[4];
    int lpoff[4];
    #pragma unroll
    for (int it = 0; it < 4; ++it) {
        const int c = tid + it * 256;
        if (c < 512) {
            const int kk = c >> 8;
            const int cr = c & 255;
            gp[it] = A + (size_t)(m0 + (cr >> 2)) * DM + kk * 32 + (c & 3) * 8;
        } else {
            const int cb = c - 512;
            const int kk = cb >> 8;
            const int cr = cb & 255;
            gp[it] = BT + (size_t)(n0 + (cr >> 2)) * DM + kk * 32 + (cb & 3) * 8;
        }
        lpoff[it] = c * 8;
    }

    // prologue: stage tile 0
    #pragma unroll
    for (int it = 0; it < 4; ++it)
        GLDS16(gp[it], &S[0][lpoff[it]]);
    __syncthreads();

    for (int t = 0; t < 8; ++t) {
        const int cur = t & 1, nxt = cur ^ 1;
        if (t < 7) {
            const int k0n = (t + 1) * GK;
            #pragma unroll
            for (int it = 0; it < 4; ++it)
                GLDS16(gp[it] + k0n, &S[nxt][lpoff[it]]);
        }

        #pragma unroll
        for (int kk = 0; kk < 2; ++kk) {
            bf16x8 af[2], bfr[2];
            #pragma unroll
            for (int i = 0; i < 2; ++i)
                af[i] = *(const bf16x8*)&S[cur][kk * 2048 + (wm + i * 16 + l15) * 32 + q8];
            #pragma unroll
            for (int j = 0; j < 2; ++j)
                bfr[j] = *(const bf16x8*)&S[cur][4096 + kk * 2048 + (wn + j * 16 + l15) * 32 + q8];
            #pragma unroll
            for (int i = 0; i < 2; ++i)
                #pragma unroll
                for (int j = 0; j < 2; ++j)
                    acc[i][j] = __builtin_amdgcn_mfma_f32_16x16x32_bf16(af[i], bfr[j], acc[i][j], 0, 0, 0);
        }
        __syncthreads();   // drains next-tile GLDS16; buf[nxt] ready
    }

    #pragma unroll
    for (int j = 0; j < 2; ++j) {
        const int col = n0 + wn + j * 16 + l15;
        const float bov = bias[col];
        #pragma unroll
        for (int i = 0; i < 2; ++i) {
            const int rbase = m0 + wm + i * 16 + (lane >> 4) * 4;
            #pragma unroll
            for (int r = 0; r < 4; ++r)
                C[(size_t)(rbase + r) * DM + col] = acc[i][j][r] + bov;
        }
    }
}

extern "C" void kernel_launch(void* const* d_in, const int* in_sizes, int n_in,
                              void* d_out, int out_size, void* d_ws, size_t ws_size,
                              hipStream_t stream) {
    const float* q  = (const float*)d_in[0];
    const float* k  = (const float*)d_in[1];
    const float* v  = (const float*)d_in[2];
    const float* Wq = (const float*)d_in[3];
    const float* bq = (const float*)d_in[4];
    const float* Wk = (const float*)d_in[5];
    const float* bk = (const float*)d_in[6];
    const float* Wv = (const float*)d_in[7];
    const float* bv = (const float*)d_in[8];
    const float* Wo = (const float*)d_in[9];
    const float* bo = (const float*)d_in[10];

    const size_t NE = (size_t)MROWS * DM;  // 2,097,152

    float* vsum = (float*)d_ws;                        // 1024 floats
    unsigned short* Qb     = (unsigned short*)(vsum + 1024);
    unsigned short* Kb     = Qb + NE;
    unsigned short* Vb     = Kb + NE;
    unsigned short* WqT    = Vb + NE;
    unsigned short* WkT    = WqT + DM * DM;
    unsigned short* WvT    = WkT + DM * DM;
    unsigned short* WoT    = WvT + DM * DM;
    unsigned short* concat = WoT + DM * DM;

    // 1. weight transpose + vsum init (small)
    prep_w<<<1024, 256, 0, stream>>>(Wq, Wk, Wv, Wo, bv, WqT, WkT, WvT, WoT, vsum);

    // 2. Q/K/V projection GEMMs, double-buffered, fused f32->bf16 A-staging + V col-sum
    gemm_qkv_cvt<<<768, 256, 0, stream>>>(q, k, v, WqT, WkT, WvT,
                                          bq, bk, bv, Qb, Kb, Vb, vsum);

    // 3. MFMA band attention -> bf16 concat (2048 waves, 8/CU), V via LDS tile
    attn_mfma<<<dim3(SEQ / 16, BS * NH), 64, 0, stream>>>(Qb, Kb, Vb, vsum, concat);

    // 4. output projection (1D grid 512, XCD-swizzled, double-buffered)
    gemm_out<<<512, 256, 0, stream>>>(concat, WoT, bo, (float*)d_out);
}